// Round 1
// baseline (46.632 us; speedup 1.0000x reference)
//
#include <hip/hip_runtime.h>

#define V 64
#define W 5
#define G 80
#define O 80
#define NROT 16
#define EPSV 1e-5f
#define NLOG2E (-1.4426950408889634f)

// One block per (b,n) point. 320 threads = 5 waves.
// Stage 2 mapping: g = tid % 80, j = tid / 80 (j = k-quad, k = 4j..4j+3).
// Stage 3 mapping: idx = w*80+o, strided over 320 threads (400 outputs).
__global__ __launch_bounds__(320) void conv_kernel(
    const float* __restrict__ feat,      // [NP][V][W]
    const float* __restrict__ rho,       // [NP][V]
    const float* __restrict__ theta,     // [NP][V]
    const float* __restrict__ mask,      // [NP][V]
    const float* __restrict__ mu_rho,    // [W][G]
    const float* __restrict__ mu_theta,  // [W][G]
    const float* __restrict__ sig_rho,   // [W][G]
    const float* __restrict__ sig_theta, // [W][G]
    const float* __restrict__ Wc,        // [W][G][O]
    const float* __restrict__ bc,        // [W][O]
    float* __restrict__ out)             // [NP][W][O]
{
    __shared__ float s_rhom[V][2];         // (rho, mask? 0 : -1e30)
    __shared__ float s_featT[V][8];        // feat[v][w], padded
    __shared__ float s_th[V][NROT];        // rotated theta per (v,k)
    __shared__ float s_desc[W][G][NROT];   // descriptor

    const int tid = threadIdx.x;
    const int p = blockIdx.x;
    const int g = tid % G;   // 0..79
    const int j = tid / G;   // 0..3 (k-quad)

    // ---- stage 1: stage point data into LDS ----
    if (tid < V) {
        s_rhom[tid][0] = rho[p * V + tid];
        s_rhom[tid][1] = (mask[p * V + tid] != 0.0f) ? 0.0f : -1e30f;
    }
    if (tid < V * W) {
        int v = tid / W, w = tid % W;
        s_featT[v][w] = feat[p * V * W + tid];
    }
    const float kstep = 0.39269908169872414f;      // 2*pi/16
    const float two_pi = 6.283185307179586f;
    const float inv_two_pi = 0.15915494309189535f;
    for (int i = tid; i < V * NROT; i += 320) {
        int v = i >> 4, k = i & 15;
        float x = theta[p * V + v] + (float)k * kstep;
        x = x - floorf(x * inv_two_pi) * two_pi;   // jnp.mod(x, 2pi)
        s_th[v][k] = x;
    }

    // uniformity check: are mu/sigma rows identical across W?
    // thread checks element (w = 1+j, g) of each of the 4 arrays.
    int pred = (mu_rho  [(1 + j) * G + g] == mu_rho  [g]) &&
               (mu_theta[(1 + j) * G + g] == mu_theta[g]) &&
               (sig_rho [(1 + j) * G + g] == sig_rho [g]) &&
               (sig_theta[(1 + j) * G + g] == sig_theta[g]);
    const int uni = __syncthreads_and(pred);   // doubles as stage-1 barrier

    // ---- stage 2: gaussian accumulation -> desc ----
    if (uni) {
        // fast path: gaussian independent of w -> one exp serves 5 channels
        const float mu_r = mu_rho[g];
        const float sr   = sig_rho[g];
        const float c_sr = NLOG2E / (sr * sr + EPSV);
        const float mu_t = mu_theta[g];
        const float st   = sig_theta[g];
        const float c_st = NLOG2E / (st * st + EPSV);

        float den[4] = {0.f, 0.f, 0.f, 0.f};
        float num[5][4];
        #pragma unroll
        for (int w = 0; w < W; ++w)
            #pragma unroll
            for (int kk = 0; kk < 4; ++kk) num[w][kk] = 0.f;

        #pragma unroll 4
        for (int v = 0; v < V; ++v) {
            float2 rm = *(const float2*)(&s_rhom[v][0]);
            float dr = rm.x - mu_r;
            float argr = fmaf(dr * dr, c_sr, rm.y);   // rho part + mask fold
            float4 fA = *(const float4*)(&s_featT[v][0]);
            float f4v = s_featT[v][4];
            float4 th4 = *(const float4*)(&s_th[v][j * 4]);
            float tv[4] = {th4.x, th4.y, th4.z, th4.w};
            #pragma unroll
            for (int kk = 0; kk < 4; ++kk) {
                float t = tv[kk] - mu_t;
                float e = __builtin_amdgcn_exp2f(fmaf(t * t, c_st, argr));
                den[kk] += e;
                num[0][kk] = fmaf(e, fA.x, num[0][kk]);
                num[1][kk] = fmaf(e, fA.y, num[1][kk]);
                num[2][kk] = fmaf(e, fA.z, num[2][kk]);
                num[3][kk] = fmaf(e, fA.w, num[3][kk]);
                num[4][kk] = fmaf(e, f4v,  num[4][kk]);
            }
        }
        float rd[4];
        #pragma unroll
        for (int kk = 0; kk < 4; ++kk)
            rd[kk] = __builtin_amdgcn_rcpf(den[kk] + EPSV);
        #pragma unroll
        for (int w = 0; w < W; ++w) {
            float4 dv = make_float4(num[w][0] * rd[0], num[w][1] * rd[1],
                                    num[w][2] * rd[2], num[w][3] * rd[3]);
            *(float4*)(&s_desc[w][g][j * 4]) = dv;
        }
    } else {
        // generic path: per-w gaussians (correctness fallback)
        #pragma unroll 1
        for (int w = 0; w < W; ++w) {
            const float mu_r = mu_rho[w * G + g];
            const float sr   = sig_rho[w * G + g];
            const float c_sr = NLOG2E / (sr * sr + EPSV);
            const float mu_t = mu_theta[w * G + g];
            const float st   = sig_theta[w * G + g];
            const float c_st = NLOG2E / (st * st + EPSV);
            float den[4] = {0.f, 0.f, 0.f, 0.f};
            float nm[4]  = {0.f, 0.f, 0.f, 0.f};
            for (int v = 0; v < V; ++v) {
                float2 rm = *(const float2*)(&s_rhom[v][0]);
                float dr = rm.x - mu_r;
                float argr = fmaf(dr * dr, c_sr, rm.y);
                float fw = s_featT[v][w];
                float4 th4 = *(const float4*)(&s_th[v][j * 4]);
                float tv[4] = {th4.x, th4.y, th4.z, th4.w};
                #pragma unroll
                for (int kk = 0; kk < 4; ++kk) {
                    float t = tv[kk] - mu_t;
                    float e = __builtin_amdgcn_exp2f(fmaf(t * t, c_st, argr));
                    den[kk] += e;
                    nm[kk] = fmaf(e, fw, nm[kk]);
                }
            }
            float4 dv;
            dv.x = nm[0] * __builtin_amdgcn_rcpf(den[0] + EPSV);
            dv.y = nm[1] * __builtin_amdgcn_rcpf(den[1] + EPSV);
            dv.z = nm[2] * __builtin_amdgcn_rcpf(den[2] + EPSV);
            dv.w = nm[3] * __builtin_amdgcn_rcpf(den[3] + EPSV);
            *(float4*)(&s_desc[w][g][j * 4]) = dv;
        }
    }

    __syncthreads();

    // ---- stage 3: out[w,o] = max_k (sum_g desc[w,g,k]*Wc[w,g,o]) + bc[w,o] ----
    for (int idx = tid; idx < W * O; idx += 320) {
        const int w = idx / O, o = idx % O;
        const float* wp = Wc + w * G * O + o;
        float acc[NROT];
        #pragma unroll
        for (int k = 0; k < NROT; ++k) acc[k] = 0.f;
        #pragma unroll 4
        for (int gg = 0; gg < G; ++gg) {
            float wcv = wp[gg * O];                 // coalesced over o
            const float* dp = &s_desc[w][gg][0];    // broadcast over o-lanes
            float4 d0 = *(const float4*)(dp + 0);
            float4 d1 = *(const float4*)(dp + 4);
            float4 d2 = *(const float4*)(dp + 8);
            float4 d3 = *(const float4*)(dp + 12);
            acc[0]  = fmaf(d0.x, wcv, acc[0]);
            acc[1]  = fmaf(d0.y, wcv, acc[1]);
            acc[2]  = fmaf(d0.z, wcv, acc[2]);
            acc[3]  = fmaf(d0.w, wcv, acc[3]);
            acc[4]  = fmaf(d1.x, wcv, acc[4]);
            acc[5]  = fmaf(d1.y, wcv, acc[5]);
            acc[6]  = fmaf(d1.z, wcv, acc[6]);
            acc[7]  = fmaf(d1.w, wcv, acc[7]);
            acc[8]  = fmaf(d2.x, wcv, acc[8]);
            acc[9]  = fmaf(d2.y, wcv, acc[9]);
            acc[10] = fmaf(d2.z, wcv, acc[10]);
            acc[11] = fmaf(d2.w, wcv, acc[11]);
            acc[12] = fmaf(d3.x, wcv, acc[12]);
            acc[13] = fmaf(d3.y, wcv, acc[13]);
            acc[14] = fmaf(d3.z, wcv, acc[14]);
            acc[15] = fmaf(d3.w, wcv, acc[15]);
        }
        float m = acc[0];
        #pragma unroll
        for (int k = 1; k < NROT; ++k) m = fmaxf(m, acc[k]);
        out[p * W * O + idx] = m + bc[idx];
    }
}

extern "C" void kernel_launch(void* const* d_in, const int* in_sizes, int n_in,
                              void* d_out, int out_size, void* d_ws, size_t ws_size,
                              hipStream_t stream) {
    const float* feat      = (const float*)d_in[0];
    const float* rho       = (const float*)d_in[1];
    const float* theta     = (const float*)d_in[2];
    const float* mask      = (const float*)d_in[3];
    const float* mu_rho    = (const float*)d_in[4];
    const float* mu_theta  = (const float*)d_in[5];
    const float* sig_rho   = (const float*)d_in[6];
    const float* sig_theta = (const float*)d_in[7];
    const float* Wc        = (const float*)d_in[8];
    const float* bc        = (const float*)d_in[9];
    float* outp            = (float*)d_out;

    const int np = in_sizes[1] / V;   // B*N points (rho is [B,N,V])
    conv_kernel<<<np, 320, 0, stream>>>(feat, rho, theta, mask, mu_rho, mu_theta,
                                        sig_rho, sig_theta, Wc, bc, outp);
}